// Round 7
// baseline (219.562 us; speedup 1.0000x reference)
//
#include <hip/hip_runtime.h>
#include <cstddef>

typedef __attribute__((ext_vector_type(8))) short bf16x8;
typedef __attribute__((ext_vector_type(4))) float f32x4;

#define MFMA(a, b, c) __builtin_amdgcn_mfma_f32_16x16x32_bf16((a), (b), (c), 0, 0, 0)

static __device__ __forceinline__ unsigned short f2bf(float f) {
  unsigned u = __builtin_bit_cast(unsigned, f);
  u = u + 0x7FFFu + ((u >> 16) & 1u);
  return (unsigned short)(u >> 16);
}
static __device__ __forceinline__ float bf2f(unsigned short h) {
  unsigned u = ((unsigned)h) << 16;
  return __builtin_bit_cast(float, u);
}
static __device__ __forceinline__ float fast_sig(float x) {
  return __builtin_amdgcn_rcpf(1.0f + __expf(-x));
}
static __device__ __forceinline__ float fast_tanh(float x) {
  return 2.0f * __builtin_amdgcn_rcpf(1.0f + __expf(-2.0f * x)) - 1.0f;
}

// LDS-only barrier (no vmcnt drain; global stores/prefetch loads stay in flight)
static __device__ __forceinline__ void lds_barrier() {
  asm volatile("s_waitcnt lgkmcnt(0)\n\ts_barrier" ::: "memory");
}

// Activation buffer: [16 batch rows][256 B = 128 bf16 k-slots], XOR-swizzled per row.
static __device__ __forceinline__ bf16x8 aread(const char* base, int lane, int kc) {
  int b = lane & 15, g = lane >> 4;
  int off = (kc * 64 + g * 16) ^ ((b & 7) << 4);
  return *(const bf16x8*)(base + b * 256 + off);
}
static __device__ __forceinline__ void awrite16(char* base, int b, int k, unsigned short v) {
  int off = (2 * k) ^ ((b & 7) << 4);
  *(unsigned short*)(base + b * 256 + off) = v;
}
static __device__ __forceinline__ void awrite32(char* base, int b, int k, unsigned v) {
  int off = (2 * k) ^ ((b & 7) << 4);
  *(unsigned*)(base + b * 256 + off) = v;
}

// 16 waves (1024 thr), 16 batch/block, grid 256 -> 4 waves/SIMD (2 x-waves + 2 h-waves).
// Producer/consumer split: x-waves (w<8) compute xpart(t+1)=bias+Wih*x(t+1) (no recurrence)
// into sP[(t+1)&1] as f32 C-seeds; h-waves (w>=8) seed acc from sP[t&1], run Whh MFMAs,
// do all transcendental cell work, publish h(t). One lds_barrier per iter.
// Phase 2: lagged pipeline over 16 waves (latent w<8, decoder 1 frag/wave, proj w>=13).
extern "C" __global__ __launch_bounds__(1024, 1)
void lstm_ae_mfma6(const float* __restrict__ x,
                   const float* __restrict__ eWih, const float* __restrict__ eWhh, const float* __restrict__ eb,
                   const float* __restrict__ lWih, const float* __restrict__ lWhh, const float* __restrict__ lb,
                   const float* __restrict__ dWih, const float* __restrict__ dWhh, const float* __restrict__ db,
                   const float* __restrict__ oW,  const float* __restrict__ ob,
                   float* __restrict__ out)
{
  __shared__ __align__(16) char sAhi[2][4096];
  __shared__ __align__(16) char sAlo[2][4096];
  __shared__ __align__(16) char sP[2][16384];   // xpart f32: [16 batch][256 gate-rows]

  const int tid  = threadIdx.x;
  const int lane = tid & 63;
  const int w    = tid >> 6;        // wave 0..15
  const int c16  = lane & 15;       // batch
  const int p4   = lane >> 4;
  const int bbase = blockIdx.x * 16;
  const bool xw = (w < 8);
  const int p   = w & 7;            // pair id: x-wave p and h-wave p share gate rows p*32..p*32+31

  // ---------- zero activation buffers ----------
  if (tid < 512) {
    f32x4 z = {0.f, 0.f, 0.f, 0.f};
    *(f32x4*)(&sAhi[0][0] + tid * 16) = z;
    *(f32x4*)(&sAlo[0][0] + tid * 16) = z;
  }

  // ---------- phase-1 weights (role-split) ----------
  // gate rows: tr=c16 -> (u = p*8+(tr>>2)*2+n, ga = tr&3)
  // x-waves: Wih chunks 0,1 (k = feature, 40..63 pad 0). h-waves: Whh chunks 2,3 (k-64 = unit).
  bf16x8 wfh[2][2], wfl[2][2];
  float ebias[2][4];
#pragma unroll
  for (int n = 0; n < 2; ++n) {
    int u = p * 8 + (c16 >> 2) * 2 + n;
    int ga = c16 & 3;
    if (xw) {
#pragma unroll
      for (int r = 0; r < 4; ++r) ebias[n][r] = eb[r * 64 + (p * 8 + p4 * 2 + n)];
    }
#pragma unroll
    for (int kci = 0; kci < 2; ++kci) {
      bf16x8 hi, lo;
#pragma unroll
      for (int e = 0; e < 8; ++e) {
        int k = kci * 32 + p4 * 8 + e;
        float v;
        if (xw) v = (k < 40) ? eWih[(ga * 64 + u) * 40 + k] : 0.0f;
        else    v = eWhh[(ga * 64 + u) * 64 + k];
        unsigned short hh = f2bf(v);
        hi[e] = (short)hh;
        lo[e] = (short)f2bf(v - bf2f(hh));
      }
      wfh[n][kci] = hi; wfl[n][kci] = lo;
    }
  }

  lds_barrier();  // zeros visible

  // ---------- stage x(0)->buf0, x(1)->buf1 (320 threads, float2 each); preload x(2) ----------
  const bool st = (tid < 320);
  const int sbb = tid / 20, sf0 = (tid % 20) * 2;
  if (st) {
#pragma unroll
    for (int tau = 0; tau < 2; ++tau) {
      float2 v = *(const float2*)(x + ((size_t)(bbase + sbb) * 100 + tau) * 40 + sf0);
      unsigned short h0 = f2bf(v.x), h1 = f2bf(v.y);
      unsigned short l0 = f2bf(v.x - bf2f(h0)), l1 = f2bf(v.y - bf2f(h1));
      awrite32(sAhi[tau], sbb, sf0, (unsigned)h0 | ((unsigned)h1 << 16));
      awrite32(sAlo[tau], sbb, sf0, (unsigned)l0 | ((unsigned)l1 << 16));
    }
  }
  float2 xin = {0.f, 0.f};
  if (st) xin = *(const float2*)(x + ((size_t)(bbase + sbb) * 100 + 2) * 40 + sf0);
  lds_barrier();

  // xpart LDS offsets (f32x4 per lane per n-frag), bank-swizzled
  const int pswz  = (c16 & 7) << 4;
  const int poff0 = (c16 * 1024 + (p * 32 + p4 * 4) * 4) ^ pswz;
  const int poff1 = (c16 * 1024 + (p * 32 + 16 + p4 * 4) * 4) ^ pswz;

  // ---------- pre-iter: xpart(0) from x(0) in buf0 ----------
  if (xw) {
    bf16x8 x0h = aread(sAhi[0], lane, 0), x0l = aread(sAlo[0], lane, 0);
    bf16x8 x1h = aread(sAhi[0], lane, 1), x1l = aread(sAlo[0], lane, 1);
#pragma unroll
    for (int n = 0; n < 2; ++n) {
      f32x4 aA = f32x4{ebias[n][0], ebias[n][1], ebias[n][2], ebias[n][3]};
      aA = MFMA(wfh[n][0], x0h, aA);
      aA = MFMA(wfl[n][0], x0h, aA);
      aA = MFMA(wfh[n][0], x0l, aA);
      f32x4 aB = f32x4{0.f, 0.f, 0.f, 0.f};
      aB = MFMA(wfh[n][1], x1h, aB);
      aB = MFMA(wfl[n][1], x1h, aB);
      aB = MFMA(wfh[n][1], x1l, aB);
      f32x4 r = aA + aB;
      *(f32x4*)(sP[0] + ((n == 0) ? poff0 : poff1)) = r;
    }
  }
  lds_barrier();

  float cE[2] = {0.f, 0.f};

  // ================= PHASE 1: 1 lds_barrier/iter, role-split =================
  // iter t: reads buf[(t+1)&1] (x-waves: x(t+1); h-waves: h(t-1)), sP[t&1] (h-waves);
  // writes sP[(t+1)&1] (x-waves), h(t)+x(t+2) -> buf[t&1].
#pragma unroll 1
  for (int t = 0; t < 100; ++t) {
    const int rb = (t + 1) & 1, wb = t & 1;
    if (xw) {
      bf16x8 x0h = aread(sAhi[rb], lane, 0), x0l = aread(sAlo[rb], lane, 0);
      bf16x8 x1h = aread(sAhi[rb], lane, 1), x1l = aread(sAlo[rb], lane, 1);
#pragma unroll
      for (int n = 0; n < 2; ++n) {
        f32x4 aA = f32x4{ebias[n][0], ebias[n][1], ebias[n][2], ebias[n][3]};
        aA = MFMA(wfh[n][0], x0h, aA);
        aA = MFMA(wfl[n][0], x0h, aA);
        aA = MFMA(wfh[n][0], x0l, aA);
        f32x4 aB = f32x4{0.f, 0.f, 0.f, 0.f};
        aB = MFMA(wfh[n][1], x1h, aB);
        aB = MFMA(wfl[n][1], x1h, aB);
        aB = MFMA(wfh[n][1], x1l, aB);
        f32x4 r = aA + aB;
        *(f32x4*)(sP[rb] + ((n == 0) ? poff0 : poff1)) = r;
      }
      // stager: write x(t+2) (regs from iter t-1), issue load x(t+3)
      if (st) {
        unsigned short h0 = f2bf(xin.x), h1 = f2bf(xin.y);
        unsigned short l0 = f2bf(xin.x - bf2f(h0)), l1 = f2bf(xin.y - bf2f(h1));
        awrite32(sAhi[wb], sbb, sf0, (unsigned)h0 | ((unsigned)h1 << 16));
        awrite32(sAlo[wb], sbb, sf0, (unsigned)l0 | ((unsigned)l1 << 16));
        int tn = (t + 3 <= 99) ? t + 3 : 99;
        xin = *(const float2*)(x + ((size_t)(bbase + sbb) * 100 + tn) * 40 + sf0);
      }
    } else {
      f32x4 acc0 = *(const f32x4*)(sP[wb] + poff0);
      f32x4 acc1 = *(const f32x4*)(sP[wb] + poff1);
      bf16x8 h2h = aread(sAhi[rb], lane, 2), h2l = aread(sAlo[rb], lane, 2);
      bf16x8 h3h = aread(sAhi[rb], lane, 3), h3l = aread(sAlo[rb], lane, 3);
      unsigned short hh[2], hl[2];
#pragma unroll
      for (int n = 0; n < 2; ++n) {
        f32x4 aA = (n == 0) ? acc0 : acc1;
        aA = MFMA(wfh[n][0], h2h, aA);
        aA = MFMA(wfl[n][0], h2h, aA);
        aA = MFMA(wfh[n][0], h2l, aA);
        f32x4 aB = f32x4{0.f, 0.f, 0.f, 0.f};
        aB = MFMA(wfh[n][1], h3h, aB);
        aB = MFMA(wfl[n][1], h3h, aB);
        aB = MFMA(wfh[n][1], h3l, aB);
        f32x4 gv = aA + aB;
        float ii = fast_sig(gv[0]), ff = fast_sig(gv[1]);
        float gg = fast_tanh(gv[2]), oo = fast_sig(gv[3]);
        cE[n] = ff * cE[n] + ii * gg;
        float hv = oo * fast_tanh(cE[n]);
        hh[n] = f2bf(hv);
        hl[n] = f2bf(hv - bf2f(hh[n]));
      }
      awrite32(sAhi[wb], c16, 64 + p * 8 + p4 * 2, (unsigned)hh[0] | ((unsigned)hh[1] << 16));
      awrite32(sAlo[wb], c16, 64 + p * 8 + p4 * 2, (unsigned)hl[0] | ((unsigned)hl[1] << 16));
    }
    lds_barrier();
  }
  // h(99) written at iter 99 -> buf[99&1] = buf1, chunks 2,3.

  // ================= xg_lat = lb + lWih @ h_enc_last (waves 0..7) =================
  f32x4 xga = {0.f, 0.f, 0.f, 0.f};
  if (w < 8) {
    int u = w * 4 + (c16 >> 2), ga = c16 & 3;
    int ul = w * 4 + p4;
    xga = f32x4{lb[ul], lb[32 + ul], lb[64 + ul], lb[96 + ul]};
#pragma unroll
    for (int kci = 0; kci < 2; ++kci) {
      bf16x8 hi, lo;
#pragma unroll
      for (int e = 0; e < 8; ++e) {
        float v = lWih[(ga * 32 + u) * 64 + kci * 32 + p4 * 8 + e];
        unsigned short hh = f2bf(v);
        hi[e] = (short)hh;
        lo[e] = (short)f2bf(v - bf2f(hh));
      }
      bf16x8 ah = aread(sAhi[1], lane, 2 + kci);
      bf16x8 al = aread(sAlo[1], lane, 2 + kci);
      xga = MFMA(hi, ah, xga);
      xga = MFMA(lo, ah, xga);
      xga = MFMA(hi, al, xga);
    }
  }
  lds_barrier();  // h_enc reads complete

  // re-zero activation buffers (h_lat(-1) = h_dec(-1) = h_dec(-2) = 0)
  if (tid < 512) {
    f32x4 z = {0.f, 0.f, 0.f, 0.f};
    *(f32x4*)(&sAhi[0][0] + tid * 16) = z;
    *(f32x4*)(&sAlo[0][0] + tid * 16) = z;
  }

  // ---------- phase-2 weights ----------
  // decoder: 1 frag/wave: frag d=w -> u = (w>>1)*8 + (c16>>2)*2 + (w&1), ga = c16&3
  bf16x8 dwh[3], dwl[3];
  float dbias[4];
  {
    int u = (w >> 1) * 8 + (c16 >> 2) * 2 + (w & 1);
    int ga = c16 & 3;
    int un = (w >> 1) * 8 + p4 * 2 + (w & 1);
#pragma unroll
    for (int r = 0; r < 4; ++r) dbias[r] = db[r * 64 + un];
#pragma unroll
    for (int kc = 0; kc < 3; ++kc) {
      bf16x8 hi, lo;
#pragma unroll
      for (int e = 0; e < 8; ++e) {
        int k = kc * 32 + p4 * 8 + e;
        float v = (k < 32) ? dWih[(ga * 64 + u) * 32 + k]
                           : dWhh[(ga * 64 + u) * 64 + (k - 32)];
        unsigned short hh = f2bf(v);
        hi[e] = (short)hh;
        lo[e] = (short)f2bf(v - bf2f(hh));
      }
      dwh[kc] = hi; dwl[kc] = lo;
    }
  }
  // latent Whh (waves 0..7): rows = latent ghat frag w
  bf16x8 lwh = {}, lwl = {};
  if (w < 8) {
    int u = w * 4 + (c16 >> 2), ga = c16 & 3;
    bf16x8 hi, lo;
#pragma unroll
    for (int e = 0; e < 8; ++e) {
      float v = lWhh[(ga * 32 + u) * 32 + p4 * 8 + e];
      unsigned short hh = f2bf(v);
      hi[e] = (short)hh;
      lo[e] = (short)f2bf(v - bf2f(hh));
    }
    lwh = hi; lwl = lo;
  }
  // projection (waves 13..15): rows = feature f = (w-13)*16 + c16
  bf16x8 pwh[2] = {}, pwl[2] = {};
  float pbias[4];
  const int wp = w - 13;
#pragma unroll
  for (int r = 0; r < 4; ++r) {
    int f = wp * 16 + p4 * 4 + r;
    pbias[r] = (w >= 13 && f < 40) ? ob[f] : 0.0f;
  }
  if (w >= 13) {
    int f = wp * 16 + c16;
#pragma unroll
    for (int kci = 0; kci < 2; ++kci) {
      bf16x8 hi, lo;
#pragma unroll
      for (int e = 0; e < 8; ++e) {
        float v = (f < 40) ? oW[f * 64 + kci * 32 + p4 * 8 + e] : 0.0f;
        unsigned short hh = f2bf(v);
        hi[e] = (short)hh;
        lo[e] = (short)f2bf(v - bf2f(hh));
      }
      pwh[kci] = hi; pwl[kci] = lo;
    }
  }

  float cL = 0.f, cD = 0.f;
  lds_barrier();

  // ================= PHASE 2: lagged pipeline, 1 lds_barrier/iter =================
  // iter i: latent t=i (w<8) | decoder t=i-1 (all) | projection t=i-2 (w>=13).
  // h_lat(t) -> buf[t&1] k 0..31; h_dec(t) -> buf[t&1] k 32..95.
#pragma unroll 1
  for (int i = 0; i < 102; ++i) {
    const int pa = i & 1;
    bf16x8 c0h = aread(sAhi[pa ^ 1], lane, 0), c0l = aread(sAlo[pa ^ 1], lane, 0);
    bf16x8 d1h = aread(sAhi[pa], lane, 1),     d1l = aread(sAlo[pa], lane, 1);
    bf16x8 d2h = aread(sAhi[pa], lane, 2),     d2l = aread(sAlo[pa], lane, 2);

    // --- latent step t=i (waves 0..7) ---
    if (i < 100 && w < 8) {
      f32x4 lac = xga;
      lac = MFMA(lwh, c0h, lac);
      lac = MFMA(lwl, c0h, lac);
      lac = MFMA(lwh, c0l, lac);
      float ii = fast_sig(lac[0]), ff = fast_sig(lac[1]);
      float gg = fast_tanh(lac[2]), oo = fast_sig(lac[3]);
      cL = ff * cL + ii * gg;
      float hv = oo * fast_tanh(cL);
      unsigned short hhh = f2bf(hv);
      awrite16(sAhi[pa], c16, w * 4 + p4, hhh);
      awrite16(sAlo[pa], c16, w * 4 + p4, f2bf(hv - bf2f(hhh)));
    }

    // --- decoder step t=i-1 (all 16 waves, 1 frag each; 3 indep 3-chains) ---
    if (i >= 1 && i < 101) {
      f32x4 dA = f32x4{dbias[0], dbias[1], dbias[2], dbias[3]};
      dA = MFMA(dwh[0], c0h, dA);
      dA = MFMA(dwl[0], c0h, dA);
      dA = MFMA(dwh[0], c0l, dA);
      f32x4 dB = f32x4{0.f, 0.f, 0.f, 0.f};
      dB = MFMA(dwh[1], d1h, dB);
      dB = MFMA(dwl[1], d1h, dB);
      dB = MFMA(dwh[1], d1l, dB);
      f32x4 dC = f32x4{0.f, 0.f, 0.f, 0.f};
      dC = MFMA(dwh[2], d2h, dC);
      dC = MFMA(dwl[2], d2h, dC);
      dC = MFMA(dwh[2], d2l, dC);
      f32x4 gv = (dA + dB) + dC;
      float ii = fast_sig(gv[0]), ff = fast_sig(gv[1]);
      float gg = fast_tanh(gv[2]), oo = fast_sig(gv[3]);
      cD = ff * cD + ii * gg;
      float hv = oo * fast_tanh(cD);
      unsigned short hhh = f2bf(hv);
      int k = 32 + (w >> 1) * 8 + p4 * 2 + (w & 1);
      awrite16(sAhi[pa ^ 1], c16, k, hhh);
      awrite16(sAlo[pa ^ 1], c16, k, f2bf(hv - bf2f(hhh)));
    }

    // --- projection t=i-2 (waves 13..15; shares d1,d2 reads) ---
    if (i >= 2 && w >= 13) {
      f32x4 pA = f32x4{pbias[0], pbias[1], pbias[2], pbias[3]};
      pA = MFMA(pwh[0], d1h, pA);
      pA = MFMA(pwl[0], d1h, pA);
      pA = MFMA(pwh[0], d1l, pA);
      f32x4 pB = f32x4{0.f, 0.f, 0.f, 0.f};
      pB = MFMA(pwh[1], d2h, pB);
      pB = MFMA(pwl[1], d2h, pB);
      pB = MFMA(pwh[1], d2l, pB);
      f32x4 pac = pA + pB;
#pragma unroll
      for (int r = 0; r < 4; ++r) {
        int f = wp * 16 + p4 * 4 + r;
        if (f < 40)
          out[((size_t)(bbase + c16) * 100 + (i - 2)) * 40 + f] = pac[r];
      }
    }
    lds_barrier();
  }
}

extern "C" void kernel_launch(void* const* d_in, const int* in_sizes, int n_in,
                              void* d_out, int out_size, void* d_ws, size_t ws_size,
                              hipStream_t stream) {
  const float* x    = (const float*)d_in[0];
  const float* eWih = (const float*)d_in[1];
  const float* eWhh = (const float*)d_in[2];
  const float* eb   = (const float*)d_in[3];
  const float* lWih = (const float*)d_in[4];
  const float* lWhh = (const float*)d_in[5];
  const float* lb   = (const float*)d_in[6];
  const float* dWih = (const float*)d_in[7];
  const float* dWhh = (const float*)d_in[8];
  const float* db   = (const float*)d_in[9];
  const float* oW   = (const float*)d_in[10];
  const float* ob   = (const float*)d_in[11];
  float* out = (float*)d_out;

  lstm_ae_mfma6<<<256, 1024, 0, stream>>>(x, eWih, eWhh, eb, lWih, lWhh, lb,
                                          dWih, dWhh, db, oW, ob, out);
}

// Round 8
// 186.935 us; speedup vs baseline: 1.1745x; 1.1745x over previous
//
#include <hip/hip_runtime.h>
#include <cstddef>

typedef __attribute__((ext_vector_type(8))) short bf16x8;
typedef __attribute__((ext_vector_type(4))) float f32x4;

#define MFMA(a, b, c) __builtin_amdgcn_mfma_f32_16x16x32_bf16((a), (b), (c), 0, 0, 0)

// ---- cheap hi/lo split ----
// hi: round-half-up to bf16, kept as f32 bit-pattern (top 16 bits valid, low 16 zero).
// bf2f(hi) is the same register reinterpreted -> free. lo = f - hi (1 sub).
static __device__ __forceinline__ unsigned hi_bits(float f) {
  unsigned u = __builtin_bit_cast(unsigned, f);
  return (u + 0x8000u) & 0xFFFF0000u;
}
static __device__ __forceinline__ float asf(unsigned u) {
  return __builtin_bit_cast(float, u);
}
// pack top halves of two f32 bit-patterns: result = (a>>16) | (b & 0xFFFF0000)
// = bf16(a) in low u16, bf16(b) in high u16 (truncation for lo-planes). 1 v_perm_b32.
static __device__ __forceinline__ unsigned pack_hi(unsigned a, unsigned b) {
  return __builtin_amdgcn_perm(b, a, 0x07060302u);
}
// legacy RNE round (weight prep only, one-time)
static __device__ __forceinline__ unsigned short f2bf(float f) {
  unsigned u = __builtin_bit_cast(unsigned, f);
  u = u + 0x7FFFu + ((u >> 16) & 1u);
  return (unsigned short)(u >> 16);
}
static __device__ __forceinline__ float bf2f(unsigned short h) {
  unsigned u = ((unsigned)h) << 16;
  return __builtin_bit_cast(float, u);
}
static __device__ __forceinline__ float fast_sig(float x) {
  return __builtin_amdgcn_rcpf(1.0f + __expf(-x));
}
static __device__ __forceinline__ float fast_tanh(float x) {
  return 2.0f * __builtin_amdgcn_rcpf(1.0f + __expf(-2.0f * x)) - 1.0f;
}

// LDS-only barrier: orders LDS ops across waves without draining vmcnt
// (out-stores / x prefetch loads stay in flight; compiler still inserts
// vmcnt waits before any USE of loaded data).
static __device__ __forceinline__ void lds_barrier() {
  asm volatile("s_waitcnt lgkmcnt(0)\n\ts_barrier" ::: "memory");
}

// Activation buffer: [16 batch rows][256 B = 128 bf16 k-slots], XOR-swizzled per row.
// B-fragment (cols = batch): lane holds col b=lane&15, k = kc*32 + (lane>>4)*8 + {0..7}.
static __device__ __forceinline__ bf16x8 aread(const char* base, int lane, int kc) {
  int b = lane & 15, g = lane >> 4;
  int off = (kc * 64 + g * 16) ^ ((b & 7) << 4);
  return *(const bf16x8*)(base + b * 256 + off);
}
static __device__ __forceinline__ void awrite16(char* base, int b, int k, unsigned short v) {
  int off = (2 * k) ^ ((b & 7) << 4);
  *(unsigned short*)(base + b * 256 + off) = v;
}
static __device__ __forceinline__ void awrite32(char* base, int b, int k, unsigned v) {
  int off = (2 * k) ^ ((b & 7) << 4);
  *(unsigned*)(base + b * 256 + off) = v;
}

// 8 waves. Weights = A-operand (rows = ghat) in VGPRs; activations = B-operand (cols = batch)
// in LDS; in-register cell update (C/D rows = 4 gates of unit u = w*8+p4*2+n).
// Encoder: 1 lds_barrier/step. Phase 2: lagged pipeline
// (latent t=i | decoder t=i-1 | projection t=i-2), 1 lds_barrier/iter.
extern "C" __global__ __launch_bounds__(512, 2)
void lstm_ae_mfma7(const float* __restrict__ x,
                   const float* __restrict__ eWih, const float* __restrict__ eWhh, const float* __restrict__ eb,
                   const float* __restrict__ lWih, const float* __restrict__ lWhh, const float* __restrict__ lb,
                   const float* __restrict__ dWih, const float* __restrict__ dWhh, const float* __restrict__ db,
                   const float* __restrict__ oW,  const float* __restrict__ ob,
                   float* __restrict__ out)
{
  __shared__ __align__(16) char sAhi[2][4096];
  __shared__ __align__(16) char sAlo[2][4096];

  const int tid  = threadIdx.x;
  const int lane = tid & 63;
  const int w    = tid >> 6;        // wave 0..7
  const int c16  = lane & 15;       // batch
  const int p4   = lane >> 4;
  const int bbase = blockIdx.x * 16;

  // ---------- zero both buffers ----------
  {
    f32x4 z = {0.f, 0.f, 0.f, 0.f};
    *(f32x4*)(&sAhi[0][0] + tid * 16) = z;
    *(f32x4*)(&sAlo[0][0] + tid * 16) = z;
  }

  // ---------- encoder weights: rows tr=c16 -> (u = w*8+(tr>>2)*2+n, ga = tr&3) ----------
  // k: 0..39 = x (chunks 0,1), 64..127 = h_enc slot 64+u (chunks 2,3)
  bf16x8 ewh[2][4], ewl[2][4];
  float ebias[2][4];
#pragma unroll
  for (int n = 0; n < 2; ++n) {
    int tr = c16;
    int u = w * 8 + (tr >> 2) * 2 + n;
    int ga = tr & 3;
#pragma unroll
    for (int r = 0; r < 4; ++r) ebias[n][r] = eb[r * 64 + (w * 8 + p4 * 2 + n)];
#pragma unroll
    for (int kc = 0; kc < 4; ++kc) {
      bf16x8 hi, lo;
#pragma unroll
      for (int e = 0; e < 8; ++e) {
        int k = kc * 32 + p4 * 8 + e;
        float v = 0.f;
        if (k < 40)       v = eWih[(ga * 64 + u) * 40 + k];
        else if (k >= 64) v = eWhh[(ga * 64 + u) * 64 + (k - 64)];
        unsigned short hh = f2bf(v);
        hi[e] = (short)hh;
        lo[e] = (short)f2bf(v - bf2f(hh));
      }
      ewh[n][kc] = hi; ewl[n][kc] = lo;
    }
  }

  lds_barrier();  // zeros visible

  // ---------- stage x_0 into buf 0 ----------
  if (tid < 160) {
    int b = tid / 10, f4 = tid - b * 10;
    f32x4 ld = *(const f32x4*)(x + ((size_t)(bbase + b) * 100 + 0) * 40 + f4 * 4);
    unsigned xh[4], xl[4];
#pragma unroll
    for (int e = 0; e < 4; ++e) {
      xh[e] = hi_bits(ld[e]);
      xl[e] = __builtin_bit_cast(unsigned, ld[e] - asf(xh[e]));
    }
    unsigned long long ph = (unsigned long long)pack_hi(xh[0], xh[1])
                          | ((unsigned long long)pack_hi(xh[2], xh[3]) << 32);
    unsigned long long pl = (unsigned long long)pack_hi(xl[0], xl[1])
                          | ((unsigned long long)pack_hi(xl[2], xl[3]) << 32);
    int off = (f4 * 8) ^ ((b & 7) << 4);
    *(unsigned long long*)(sAhi[0] + b * 256 + off) = ph;
    *(unsigned long long*)(sAlo[0] + b * 256 + off) = pl;
  }

  float cE[2] = {0.f, 0.f};
  int q = 0;
  lds_barrier();

  // ================= PHASE 1: encoder, 1 lds_barrier/step =================
#pragma unroll 1
  for (int t = 0; t < 100; ++t) {
    f32x4 xld;
    int sb = 0, sf4 = 0;
    const bool stager = (tid < 160);
    if (stager) {
      int tn = (t + 1 < 100) ? t + 1 : 99;
      sb = tid / 10; sf4 = tid - sb * 10;
      xld = *(const f32x4*)(x + ((size_t)(bbase + sb) * 100 + tn) * 40 + sf4 * 4);
    }

    f32x4 acc[2], acc2[2];
#pragma unroll
    for (int n = 0; n < 2; ++n) {
      acc[n]  = f32x4{ebias[n][0], ebias[n][1], ebias[n][2], ebias[n][3]};
      acc2[n] = f32x4{0.f, 0.f, 0.f, 0.f};
    }
    const char* Ah = sAhi[q];
    const char* Al = sAlo[q];
    __builtin_amdgcn_s_setprio(1);
#pragma unroll
    for (int kc = 0; kc < 4; ++kc) {
      bf16x8 ah = aread(Ah, lane, kc);
      bf16x8 al = aread(Al, lane, kc);
#pragma unroll
      for (int n = 0; n < 2; ++n) {
        f32x4 t0 = (kc < 2) ? acc[n] : acc2[n];
        t0 = MFMA(ewh[n][kc], ah, t0);
        t0 = MFMA(ewl[n][kc], ah, t0);
        t0 = MFMA(ewh[n][kc], al, t0);
        if (kc < 2) acc[n] = t0; else acc2[n] = t0;
      }
    }
    __builtin_amdgcn_s_setprio(0);

    char* AhN = sAhi[q ^ 1];
    char* AlN = sAlo[q ^ 1];
    unsigned hhb[2], hlb[2];
#pragma unroll
    for (int n = 0; n < 2; ++n) {
      f32x4 gv = acc[n] + acc2[n];
      float ii = fast_sig(gv[0]), ff = fast_sig(gv[1]);
      float gg = fast_tanh(gv[2]), oo = fast_sig(gv[3]);
      cE[n] = ff * cE[n] + ii * gg;
      float hv = oo * fast_tanh(cE[n]);
      hhb[n] = hi_bits(hv);
      hlb[n] = __builtin_bit_cast(unsigned, hv - asf(hhb[n]));
    }
    awrite32(AhN, c16, 64 + w * 8 + p4 * 2, pack_hi(hhb[0], hhb[1]));
    awrite32(AlN, c16, 64 + w * 8 + p4 * 2, pack_hi(hlb[0], hlb[1]));

    if (stager) {
      unsigned xh[4], xl[4];
#pragma unroll
      for (int e = 0; e < 4; ++e) {
        xh[e] = hi_bits(xld[e]);
        xl[e] = __builtin_bit_cast(unsigned, xld[e] - asf(xh[e]));
      }
      unsigned long long ph = (unsigned long long)pack_hi(xh[0], xh[1])
                            | ((unsigned long long)pack_hi(xh[2], xh[3]) << 32);
      unsigned long long pl = (unsigned long long)pack_hi(xl[0], xl[1])
                            | ((unsigned long long)pack_hi(xl[2], xl[3]) << 32);
      int off = (sf4 * 8) ^ ((sb & 7) << 4);
      *(unsigned long long*)(AhN + sb * 256 + off) = ph;
      *(unsigned long long*)(AlN + sb * 256 + off) = pl;
    }
    lds_barrier();
    q ^= 1;
  }

  // ================= xg_lat = lb + lWih @ h_enc_last =================
  f32x4 xga;
  {
    int tr = c16;
    int u = w * 4 + (tr >> 2), ga = tr & 3;
    int ul = w * 4 + p4;
    xga = f32x4{lb[ul], lb[32 + ul], lb[64 + ul], lb[96 + ul]};
#pragma unroll
    for (int kci = 0; kci < 2; ++kci) {
      bf16x8 hi, lo;
#pragma unroll
      for (int e = 0; e < 8; ++e) {
        float v = lWih[(ga * 32 + u) * 64 + kci * 32 + p4 * 8 + e];
        unsigned short hh = f2bf(v);
        hi[e] = (short)hh;
        lo[e] = (short)f2bf(v - bf2f(hh));
      }
      bf16x8 ah = aread(sAhi[q], lane, 2 + kci);
      bf16x8 al = aread(sAlo[q], lane, 2 + kci);
      xga = MFMA(hi, ah, xga);
      xga = MFMA(lo, ah, xga);
      xga = MFMA(hi, al, xga);
    }
  }
  lds_barrier();  // h_enc reads complete before re-zero

  // re-zero both buffers (h_lat(-1) = h_dec(-1) = h_dec(-2) = 0)
  {
    f32x4 z = {0.f, 0.f, 0.f, 0.f};
    *(f32x4*)(&sAhi[0][0] + tid * 16) = z;
    *(f32x4*)(&sAlo[0][0] + tid * 16) = z;
  }

  // ---------- phase-2 weights ----------
  bf16x8 lwh, lwl;
  {
    int tr = c16;
    int u = w * 4 + (tr >> 2), ga = tr & 3;
    bf16x8 hi, lo;
#pragma unroll
    for (int e = 0; e < 8; ++e) {
      float v = lWhh[(ga * 32 + u) * 32 + p4 * 8 + e];
      unsigned short hh = f2bf(v);
      hi[e] = (short)hh;
      lo[e] = (short)f2bf(v - bf2f(hh));
    }
    lwh = hi; lwl = lo;
  }
  bf16x8 dwh[2][3], dwl[2][3];
  float dbias[2][4];
#pragma unroll
  for (int n = 0; n < 2; ++n) {
    int tr = c16;
    int u = w * 8 + (tr >> 2) * 2 + n;
    int ga = tr & 3;
#pragma unroll
    for (int r = 0; r < 4; ++r) dbias[n][r] = db[r * 64 + (w * 8 + p4 * 2 + n)];
#pragma unroll
    for (int kc = 0; kc < 3; ++kc) {
      bf16x8 hi, lo;
#pragma unroll
      for (int e = 0; e < 8; ++e) {
        int k = kc * 32 + p4 * 8 + e;
        float v = (k < 32) ? dWih[(ga * 64 + u) * 32 + k]
                           : dWhh[(ga * 64 + u) * 64 + (k - 32)];
        unsigned short hh = f2bf(v);
        hi[e] = (short)hh;
        lo[e] = (short)f2bf(v - bf2f(hh));
      }
      dwh[n][kc] = hi; dwl[n][kc] = lo;
    }
  }
  bf16x8 pwh[2], pwl[2];
  float pbias[4];
#pragma unroll
  for (int r = 0; r < 4; ++r) {
    int f = w * 16 + p4 * 4 + r;
    pbias[r] = (w < 3 && f < 40) ? ob[f] : 0.0f;
  }
  if (w < 3) {
    int f = w * 16 + c16;
#pragma unroll
    for (int kci = 0; kci < 2; ++kci) {
      bf16x8 hi, lo;
#pragma unroll
      for (int e = 0; e < 8; ++e) {
        float v = (f < 40) ? oW[f * 64 + kci * 32 + p4 * 8 + e] : 0.0f;
        unsigned short hh = f2bf(v);
        hi[e] = (short)hh;
        lo[e] = (short)f2bf(v - bf2f(hh));
      }
      pwh[kci] = hi; pwl[kci] = lo;
    }
  }

  float cL = 0.f;
  float cD[2] = {0.f, 0.f};
  lds_barrier();

  // ================= PHASE 2: lagged pipeline, 1 lds_barrier/iter =================
  // iter i: latent t=i | decoder t=i-1 | projection t=i-2.
  // h_lat(t) -> buf[t&1] k 0..31; h_dec(t) -> buf[t&1] k 32..95.
#pragma unroll 1
  for (int i = 0; i < 102; ++i) {
    const int pa = i & 1;
    bf16x8 c0h = aread(sAhi[pa ^ 1], lane, 0), c0l = aread(sAlo[pa ^ 1], lane, 0);
    bf16x8 d1h = aread(sAhi[pa], lane, 1),     d1l = aread(sAlo[pa], lane, 1);
    bf16x8 d2h = aread(sAhi[pa], lane, 2),     d2l = aread(sAlo[pa], lane, 2);

    // --- latent step t=i (reads h_lat(i-1) = c0) ---
    if (i < 100) {
      __builtin_amdgcn_s_setprio(1);
      f32x4 lac = xga;
      lac = MFMA(lwh, c0h, lac);
      lac = MFMA(lwl, c0h, lac);
      lac = MFMA(lwh, c0l, lac);
      __builtin_amdgcn_s_setprio(0);
      float ii = fast_sig(lac[0]), ff = fast_sig(lac[1]);
      float gg = fast_tanh(lac[2]), oo = fast_sig(lac[3]);
      cL = ff * cL + ii * gg;
      float hv = oo * fast_tanh(cL);
      unsigned hb = hi_bits(hv);
      float lov = hv - asf(hb);
      awrite16(sAhi[pa], c16, w * 4 + p4, (unsigned short)(hb >> 16));
      awrite16(sAlo[pa], c16, w * 4 + p4,
               (unsigned short)(__builtin_bit_cast(unsigned, lov) >> 16));
    }

    // --- decoder step t=i-1 (reads h_lat(i-1) = c0, h_dec(i-2) = d1,d2) ---
    if (i >= 1 && i < 101) {
      unsigned hhb[2], hlb[2];
#pragma unroll
      for (int n = 0; n < 2; ++n) {
        f32x4 dac = f32x4{dbias[n][0], dbias[n][1], dbias[n][2], dbias[n][3]};
        __builtin_amdgcn_s_setprio(1);
        dac = MFMA(dwh[n][0], c0h, dac);
        dac = MFMA(dwl[n][0], c0h, dac);
        dac = MFMA(dwh[n][0], c0l, dac);
        dac = MFMA(dwh[n][1], d1h, dac);
        dac = MFMA(dwl[n][1], d1h, dac);
        dac = MFMA(dwh[n][1], d1l, dac);
        dac = MFMA(dwh[n][2], d2h, dac);
        dac = MFMA(dwl[n][2], d2h, dac);
        dac = MFMA(dwh[n][2], d2l, dac);
        __builtin_amdgcn_s_setprio(0);
        float ii = fast_sig(dac[0]), ff = fast_sig(dac[1]);
        float gg = fast_tanh(dac[2]), oo = fast_sig(dac[3]);
        cD[n] = ff * cD[n] + ii * gg;
        float hv = oo * fast_tanh(cD[n]);
        hhb[n] = hi_bits(hv);
        hlb[n] = __builtin_bit_cast(unsigned, hv - asf(hhb[n]));
      }
      awrite32(sAhi[pa ^ 1], c16, 32 + w * 8 + p4 * 2, pack_hi(hhb[0], hhb[1]));
      awrite32(sAlo[pa ^ 1], c16, 32 + w * 8 + p4 * 2, pack_hi(hlb[0], hlb[1]));
    }

    // --- projection t=i-2 (reads h_dec(i-2) = d1,d2; shares the reads) ---
    if (i >= 2 && w < 3) {
      f32x4 pac = f32x4{pbias[0], pbias[1], pbias[2], pbias[3]};
      __builtin_amdgcn_s_setprio(1);
      pac = MFMA(pwh[0], d1h, pac);
      pac = MFMA(pwl[0], d1h, pac);
      pac = MFMA(pwh[0], d1l, pac);
      pac = MFMA(pwh[1], d2h, pac);
      pac = MFMA(pwl[1], d2h, pac);
      pac = MFMA(pwh[1], d2l, pac);
      __builtin_amdgcn_s_setprio(0);
#pragma unroll
      for (int r = 0; r < 4; ++r) {
        int f = w * 16 + p4 * 4 + r;
        if (f < 40)
          out[((size_t)(bbase + c16) * 100 + (i - 2)) * 40 + f] = pac[r];
      }
    }
    lds_barrier();
  }
}

extern "C" void kernel_launch(void* const* d_in, const int* in_sizes, int n_in,
                              void* d_out, int out_size, void* d_ws, size_t ws_size,
                              hipStream_t stream) {
  const float* x    = (const float*)d_in[0];
  const float* eWih = (const float*)d_in[1];
  const float* eWhh = (const float*)d_in[2];
  const float* eb   = (const float*)d_in[3];
  const float* lWih = (const float*)d_in[4];
  const float* lWhh = (const float*)d_in[5];
  const float* lb   = (const float*)d_in[6];
  const float* dWih = (const float*)d_in[7];
  const float* dWhh = (const float*)d_in[8];
  const float* db   = (const float*)d_in[9];
  const float* oW   = (const float*)d_in[10];
  const float* ob   = (const float*)d_in[11];
  float* out = (float*)d_out;

  lstm_ae_mfma7<<<256, 512, 0, stream>>>(x, eWih, eWhh, eb, lWih, lWhh, lb,
                                         dWih, dWhh, db, oW, ob, out);
}